// Round 9
// baseline (437.523 us; speedup 1.0000x reference)
//
#include <hip/hip_runtime.h>
#include <hip/hip_cooperative_groups.h>
#include <math.h>

namespace cg = cooperative_groups;

typedef unsigned int u32;
typedef unsigned short u16;
typedef unsigned long long u64;

#define HW    30720     // 96*320
#define W_    320
#define H_    96
#define B_    16
#define KTOP  100
#define NIMG  192       // 16*3 (hm) + 16*9 (hm_hp)
#define BPR   30        // segments per row-image (7680 quads / 256)
#define NSEGT (NIMG * BPR)   // 5760 segments
#define BCAP  256       // per-segment survivor capacity (expected ~113, ~14 sigma)
#define GRID  768       // cooperative grid (3 blocks/CU; LDS allows 4)
#define THR   256

// Shared memory reused across the three phases (max ~33 KB -> 4 blocks/CU).
union SMem {
    struct { u64 lc[BCAP]; u32 lcnt; } a;                       // NMS
    struct { u32 hist[4096]; u64 cand2[2048];                   // select
             u32 cnts[BPR]; u32 selb1, selG1, selb2, cnt2; } b;
    struct { u64 arr[300]; u64 selv[KTOP];                      // decode
             float hsv[KTOP], hxv[KTOP], hyv[KTOP]; } c;
};

// ---------------------------------------------------------------------------
// One cooperative launch, three phases separated by grid.sync():
//  A: sigmoid + 3x3 NMS (R8 float4 stencil), grid-stride over 5760 segments,
//     survivors to private global segments (deterministic ownership).
//  B: blocks 0..191: exact per-row top-100 (lax.top_k semantics) — two-round
//     radix cut (R8-validated scans) over the L2-resident segments, compact,
//     rank-select (exact: packed keys distinct; ranks a permutation).
//  C: blocks 0..143: decode (R8-validated logic, 256-thread role split).
// ---------------------------------------------------------------------------
__global__ __launch_bounds__(THR, 3) void km3d_kernel(
    const float* __restrict__ hm,   const float* __restrict__ wh,
    const float* __restrict__ hps,  const float* __restrict__ dimp,
    const float* __restrict__ rot,  const float* __restrict__ prob,
    const float* __restrict__ reg,  const float* __restrict__ hm_hp,
    const float* __restrict__ hpo,  float* __restrict__ det,
    u64* __restrict__ segbuf, u32* __restrict__ segcnt,
    u32* __restrict__ tkKey,  u32* __restrict__ tkIdx)
{
    const int bid = blockIdx.x;
    const int tid = threadIdx.x;
    const int lane = tid & 63;
    __shared__ SMem sm;
    cg::grid_group grid = cg::this_grid();

    // ================= Phase A: NMS =================
    for (int seg = bid; seg < NSEGT; seg += gridDim.x) {
        if (tid == 0) sm.a.lcnt = 0;
        __syncthreads();
        const int img = seg / BPR;
        const int sub = seg - img * BPR;
        const float* __restrict__ base = (img < 48)
            ? (hm + (size_t)img * HW) : (hm_hp + (size_t)(img - 48) * HW);
        int qi = sub * 256 + tid;           // quad index 0..7679
        int y  = qi / 80;
        int qx = qi - y * 80;
        int x0 = qx * 4;
        const float* rm = base + (y > 0 ? y - 1 : 0) * W_;
        const float* rc = base + y * W_;
        const float* rp = base + (y < H_ - 1 ? y + 1 : H_ - 1) * W_;
        float4 am = *(const float4*)(rm + x0);
        float4 ac = *(const float4*)(rc + x0);
        float4 ap = *(const float4*)(rp + x0);
        float cm0 = fmaxf(fmaxf(am.x, ac.x), ap.x);
        float cm1 = fmaxf(fmaxf(am.y, ac.y), ap.y);
        float cm2 = fmaxf(fmaxf(am.z, ac.z), ap.z);
        float cm3 = fmaxf(fmaxf(am.w, ac.w), ap.w);
        float cl, cr;
        if (qx > 0)
            cl = fmaxf(fmaxf(rm[x0 - 1], rc[x0 - 1]), rp[x0 - 1]);
        else cl = cm0;
        if (qx < 79)
            cr = fmaxf(fmaxf(rm[x0 + 4], rc[x0 + 4]), rp[x0 + 4]);
        else cr = cm3;
        float cen[4] = {ac.x, ac.y, ac.z, ac.w};
        float mx[4];
        mx[0] = fmaxf(fmaxf(cl,  cm0), cm1);
        mx[1] = fmaxf(fmaxf(cm0, cm1), cm2);
        mx[2] = fmaxf(fmaxf(cm1, cm2), cm3);
        mx[3] = fmaxf(fmaxf(cm2, cm3), cr);
        #pragma unroll
        for (int j = 0; j < 4; ++j) {
            if (cen[j] == mx[j]) {
                float s = 1.0f / (1.0f + expf(-cen[j]));   // validated expr
                u32 pix = (u32)(y * W_ + x0 + j);
                u32 p = atomicAdd(&sm.a.lcnt, 1u);
                if (p < BCAP)
                    sm.a.lc[p] = ((u64)__float_as_uint(s) << 32) | (u32)(~pix);
            }
        }
        __syncthreads();
        u32 c = sm.a.lcnt; if (c > BCAP) c = BCAP;
        if (tid < c) segbuf[(size_t)seg * BCAP + tid] = sm.a.lc[tid];
        if (tid == 0) segcnt[seg] = c;
        __syncthreads();
    }
    __threadfence();
    grid.sync();

    // ================= Phase B: select (blocks 0..191) =================
    if (bid < NIMG) {
        const int row = bid;
        const u64* __restrict__ rowseg = segbuf + (size_t)row * BPR * BCAP;
        if (tid == 0) sm.b.cnt2 = 0;
        if (tid < BPR) sm.b.cnts[tid] = segcnt[row * BPR + tid];
        for (int i = tid; i < 4096; i += THR) sm.b.hist[i] = 0;
        __syncthreads();

        // round 1: histogram key[31:20]
        for (int i = tid; i < BPR * BCAP; i += THR) {
            int s = i >> 8, l = i & (BCAP - 1);
            if ((u32)l < sm.b.cnts[s])
                atomicAdd(&sm.b.hist[(u32)(rowseg[i] >> 52)], 1u);
        }
        __syncthreads();
        if (tid < 64) {
            u32 v[4], t[4];
            #pragma unroll
            for (int k = 0; k < 4; ++k) {
                u32 s = 0; int b0 = (lane * 4 + k) * 16;
                #pragma unroll
                for (int qq = 0; qq < 16; ++qq) s += sm.b.hist[b0 + qq];
                v[k] = s;
            }
            t[3] = v[3]; t[2] = v[2] + t[3]; t[1] = v[1] + t[2]; t[0] = v[0] + t[1];
            u32 lt = t[0], s = lt;
            #pragma unroll
            for (int d = 1; d < 64; d <<= 1) {
                u32 o = __shfl_down(s, d);
                if (lane + d < 64) s += o;
            }
            u32 SH = s - lt;
            u32 sfx[5] = {t[0] + SH, t[1] + SH, t[2] + SH, t[3] + SH, SH};
            #pragma unroll
            for (int k = 0; k < 4; ++k) {
                if (sfx[k] >= KTOP && sfx[k + 1] < KTOP) {
                    u32 run = sfx[k + 1];
                    int c = lane * 4 + k;
                    for (int bin = c * 16 + 15; bin >= c * 16; --bin) {
                        u32 h = sm.b.hist[bin];
                        if (run + h >= KTOP) { sm.b.selb1 = (u32)bin; sm.b.selG1 = run; break; }
                        run += h;
                    }
                }
            }
        }
        __syncthreads();
        const u32 b1 = sm.b.selb1, G1 = sm.b.selG1;

        // round 2: histogram key[19:8] within bin b1
        for (int i = tid; i < 4096; i += THR) sm.b.hist[i] = 0;
        __syncthreads();
        for (int i = tid; i < BPR * BCAP; i += THR) {
            int s = i >> 8, l = i & (BCAP - 1);
            if ((u32)l < sm.b.cnts[s]) {
                u32 k = (u32)(rowseg[i] >> 32);
                if ((k >> 20) == b1) atomicAdd(&sm.b.hist[(k >> 8) & 0xFFFu], 1u);
            }
        }
        __syncthreads();
        {
            const u32 K2 = KTOP - G1;                 // >= 1
            if (tid < 64) {
                u32 v[4], t[4];
                #pragma unroll
                for (int k = 0; k < 4; ++k) {
                    u32 s = 0; int b0 = (lane * 4 + k) * 16;
                    #pragma unroll
                    for (int qq = 0; qq < 16; ++qq) s += sm.b.hist[b0 + qq];
                    v[k] = s;
                }
                t[3] = v[3]; t[2] = v[2] + t[3]; t[1] = v[1] + t[2]; t[0] = v[0] + t[1];
                u32 lt = t[0], s = lt;
                #pragma unroll
                for (int d = 1; d < 64; d <<= 1) {
                    u32 o = __shfl_down(s, d);
                    if (lane + d < 64) s += o;
                }
                u32 SH = s - lt;
                u32 sfx[5] = {t[0] + SH, t[1] + SH, t[2] + SH, t[3] + SH, SH};
                #pragma unroll
                for (int k = 0; k < 4; ++k) {
                    if (sfx[k] >= K2 && sfx[k + 1] < K2) {
                        u32 run = sfx[k + 1];
                        int c = lane * 4 + k;
                        for (int bin = c * 16 + 15; bin >= c * 16; --bin) {
                            u32 h = sm.b.hist[bin];
                            if (run + h >= K2) { sm.b.selb2 = (u32)bin; break; }
                            run += h;
                        }
                    }
                }
            }
        }
        __syncthreads();
        const u32 cut24 = (b1 << 12) | sm.b.selb2;

        // compact qualifiers (key[31:8] >= cut24)
        for (int i = tid; i < BPR * BCAP; i += THR) {
            int s = i >> 8, l = i & (BCAP - 1);
            if ((u32)l < sm.b.cnts[s]) {
                u64 v = rowseg[i];
                if ((u32)(v >> 40) >= cut24) {
                    u32 p = atomicAdd(&sm.b.cnt2, 1u);     // ~120 ops total
                    if (p < 2048) sm.b.cand2[p] = v;
                }
            }
        }
        __syncthreads();
        u32 q = sm.b.cnt2; if (q > 2048) q = 2048;

        // rank-select (exact top-100, value desc / idx asc), q <= 2048
        for (u32 ii = tid; ii < q; ii += THR) {
            u64 v = sm.b.cand2[ii];
            u32 rank = 0;
            for (u32 i = 0; i < q; ++i) rank += (sm.b.cand2[i] > v);
            if (rank < KTOP) {
                tkKey[row * KTOP + rank] = (u32)(v >> 32);
                tkIdx[row * KTOP + rank] = ~(u32)v;
            }
        }
    }
    __threadfence();
    grid.sync();

    // ================= Phase C: decode (blocks 0..143) =================
    if (bid < B_ * 9) {
        const int b = bid / 9;
        const int j = bid - b * 9;

        if (tid < 300) {
            int c = tid / 100, r = tid - c * 100;
            u32 key = tkKey[(b * 3 + c) * KTOP + r];
            sm.c.arr[tid] = ((u64)key << 32) | (u32)(~(u32)tid);   // tid == c*K + r
        }
        // (THR==256 covers tid<256; handle 256..299 below)
        for (int i = 256 + tid; i < 300; i += THR) {
            int c = i / 100, r = i - c * 100;
            u32 key = tkKey[(b * 3 + c) * KTOP + r];
            sm.c.arr[i] = ((u64)key << 32) | (u32)(~(u32)i);
        }
        __syncthreads();
        for (int ii = tid; ii < 300; ii += THR) {
            u64 v = sm.c.arr[ii];
            u32 rank = 0;
            for (int i = 0; i < 300; ++i) rank += (sm.c.arr[i] > v);
            if (rank < KTOP) sm.c.selv[rank] = v;
        }
        __syncthreads();

        float l = 0.f, t = 0.f, rr = 0.f, bb = 0.f, kxr = 0.f, kyr = 0.f;

        if (tid < KTOP) {
            int k = tid;
            u64 v = sm.c.selv[k];
            u32 pos = ~(u32)v;
            if (pos > 299u) pos = 299u;
            u32 key = (u32)(v >> 32);
            int c = (int)pos / 100, r = (int)pos - c * 100;
            u32 sid = tkIdx[(b * 3 + c) * KTOP + r];
            if (sid > HW - 1) sid = HW - 1;
            float score = __uint_as_float(key);
            int yy = (int)sid / W_, xx = (int)sid - yy * W_;
            float xs0 = (float)xx, ys0 = (float)yy;
            float r0 = reg[((size_t)b * 2 + 0) * HW + sid];
            float r1 = reg[((size_t)b * 2 + 1) * HW + sid];
            float xsv = xs0 + r0, ysv = ys0 + r1;
            float w0 = wh[((size_t)b * 2 + 0) * HW + sid];
            float w1 = wh[((size_t)b * 2 + 1) * HW + sid];
            l  = xsv - w0 * 0.5f;
            t  = ysv - w1 * 0.5f;
            rr = xsv + w0 * 0.5f;
            bb = ysv + w1 * 0.5f;
            kxr = hps[((size_t)b * 18 + 2 * j)     * HW + sid] + xs0;
            kyr = hps[((size_t)b * 18 + 2 * j + 1) * HW + sid] + ys0;
            if (j == 0) {
                float* o = det + ((size_t)b * KTOP + k) * 45;
                o[0] = l * 4.0f; o[1] = t * 4.0f; o[2] = rr * 4.0f; o[3] = bb * 4.0f;
                o[4] = score;
                o[44] = (float)c;
            }
        } else if (tid < 200) {
            int r = tid - 100;
            int rw = 48 + b * 9 + j;
            u32 key = tkKey[rw * KTOP + r];
            u32 idx = tkIdx[rw * KTOP + r];
            if (idx > HW - 1) idx = HW - 1;
            float s = __uint_as_float(key);
            int yy = (int)idx / W_, xx = (int)idx - yy * W_;
            float hx = (float)xx + hpo[((size_t)b * 2 + 0) * HW + idx];
            float hy = (float)yy + hpo[((size_t)b * 2 + 1) * HW + idx];
            bool valid = s > 0.1f;
            sm.c.hsv[r] = valid ? s : -1.0f;
            sm.c.hxv[r] = valid ? hx : -10000.0f;
            sm.c.hyv[r] = valid ? hy : -10000.0f;
        } else if (j == 0) {
            for (int k = tid - 200; k < KTOP; k += 56) {
                u64 v = sm.c.selv[k];
                u32 pos = ~(u32)v;
                if (pos > 299u) pos = 299u;
                int c = (int)pos / 100, r = (int)pos - c * 100;
                u32 sid = tkIdx[(b * 3 + c) * KTOP + r];
                if (sid > HW - 1) sid = HW - 1;
                float* o = det + ((size_t)b * KTOP + k) * 45;
                #pragma unroll
                for (int qq = 0; qq < 3; ++qq)
                    o[23 + qq] = dimp[((size_t)b * 3 + qq) * HW + sid];
                #pragma unroll
                for (int qq = 0; qq < 8; ++qq)
                    o[35 + qq] = rot[((size_t)b * 8 + qq) * HW + sid];
                o[43] = prob[(size_t)b * HW + sid];
            }
        }
        __syncthreads();

        if (tid < KTOP) {
            int k = tid;
            float best = INFINITY; int bi = 0;
            for (int m = 0; m < 100; ++m) {
                float dx = kxr - sm.c.hxv[m];
                float dy = kyr - sm.c.hyv[m];
                float d2 = __fadd_rn(__fmul_rn(dx, dx), __fmul_rn(dy, dy));
                float d = __fsqrt_rn(d2);
                if (d < best) { best = d; bi = m; }
            }
            float ss = sm.c.hsv[bi], hx = sm.c.hxv[bi], hy = sm.c.hyv[bi];
            float th = __fmul_rn(fmaxf(__fsub_rn(bb, t), __fsub_rn(rr, l)), 0.3f);
            bool invalid = (hx < l) | (hx > rr) | (hy < t) | (hy > bb) |
                           (ss < 0.1f) | (best > th);
            float ox = invalid ? kxr : hx;
            float oy = invalid ? kyr : hy;
            float* o = det + ((size_t)b * KTOP + k) * 45;
            o[5 + 2 * j] = ox * 4.0f;
            o[6 + 2 * j] = oy * 4.0f;
            o[26 + j]    = ss;
        }
    }
}

// ---------------------------------------------------------------------------
extern "C" void kernel_launch(void* const* d_in, const int* in_sizes, int n_in,
                              void* d_out, int out_size, void* d_ws, size_t ws_size,
                              hipStream_t stream) {
    const float* hm    = (const float*)d_in[0];
    const float* wh    = (const float*)d_in[1];
    const float* hps   = (const float*)d_in[2];
    const float* dimp  = (const float*)d_in[3];
    const float* rot   = (const float*)d_in[4];
    const float* prob  = (const float*)d_in[5];
    const float* reg   = (const float*)d_in[6];
    const float* hm_hp = (const float*)d_in[7];
    const float* hpo   = (const float*)d_in[8];
    float* det = (float*)d_out;

    u64* segbuf = (u64*)d_ws;                                  // 5760*256 u64
    u32* segcnt = (u32*)(segbuf + (size_t)NSEGT * BCAP);       // 5760 u32
    u32* tkKey  = segcnt + NSEGT;                              // 192*100 u32
    u32* tkIdx  = tkKey + NIMG * KTOP;                         // 192*100 u32

    void* args[] = { (void*)&hm, (void*)&wh, (void*)&hps, (void*)&dimp,
                     (void*)&rot, (void*)&prob, (void*)&reg, (void*)&hm_hp,
                     (void*)&hpo, (void*)&det, (void*)&segbuf, (void*)&segcnt,
                     (void*)&tkKey, (void*)&tkIdx };
    hipLaunchCooperativeKernel((const void*)km3d_kernel, dim3(GRID), dim3(THR),
                               args, 0, stream);
}

// Round 10
// 154.240 us; speedup vs baseline: 2.8366x; 2.8366x over previous
//
#include <hip/hip_runtime.h>
#include <math.h>

typedef unsigned int u32;
typedef unsigned short u16;
typedef unsigned long long u64;

#define HW    30720     // 96*320
#define W_    320
#define H_    96
#define B_    16
#define KTOP  100
#define NIMG  192       // 16*3 (hm) + 16*9 (hm_hp)
#define BPR   30        // blocks per row-image in K1 (7680 quads / 256)
#define BCAP  256       // per-block survivor segment (expected ~113, ~14 sigma)
#define NTHR  1024      // K2 threads

// ---------------------------------------------------------------------------
// K1: sigmoid + 3x3 NMS (validated float4 stencil), 1 quad per thread,
// 5760 blocks. Survivors compacted block-locally, then written to the block's
// PRIVATE global segment; count written unconditionally (poison-safe, no
// cross-block atomics, fully deterministic slot ownership).
// ---------------------------------------------------------------------------
__global__ __launch_bounds__(256) void nms_kernel(
    const float* __restrict__ hm, const float* __restrict__ hm_hp,
    u64* __restrict__ segbuf, u32* __restrict__ segcnt)
{
    const int gb  = blockIdx.x;
    const int img = gb / BPR;
    const int sub = gb - img * BPR;
    const int tid = threadIdx.x;

    __shared__ u32 lcnt;
    __shared__ u64 lc[BCAP];
    if (tid == 0) lcnt = 0;
    __syncthreads();

    const float* __restrict__ base = (img < 48)
        ? (hm + (size_t)img * HW) : (hm_hp + (size_t)(img - 48) * HW);

    int qi = sub * 256 + tid;           // quad index 0..7679
    int y  = qi / 80;
    int qx = qi - y * 80;
    int x0 = qx * 4;
    const float* rm = base + (y > 0 ? y - 1 : 0) * W_;
    const float* rc = base + y * W_;
    const float* rp = base + (y < H_ - 1 ? y + 1 : H_ - 1) * W_;
    float4 am = *(const float4*)(rm + x0);
    float4 ac = *(const float4*)(rc + x0);
    float4 ap = *(const float4*)(rp + x0);
    float cm0 = fmaxf(fmaxf(am.x, ac.x), ap.x);
    float cm1 = fmaxf(fmaxf(am.y, ac.y), ap.y);
    float cm2 = fmaxf(fmaxf(am.z, ac.z), ap.z);
    float cm3 = fmaxf(fmaxf(am.w, ac.w), ap.w);
    float cl, cr;
    if (qx > 0)
        cl = fmaxf(fmaxf(rm[x0 - 1], rc[x0 - 1]), rp[x0 - 1]);
    else cl = cm0;
    if (qx < 79)
        cr = fmaxf(fmaxf(rm[x0 + 4], rc[x0 + 4]), rp[x0 + 4]);
    else cr = cm3;

    float cen[4] = {ac.x, ac.y, ac.z, ac.w};
    float mx[4];
    mx[0] = fmaxf(fmaxf(cl,  cm0), cm1);
    mx[1] = fmaxf(fmaxf(cm0, cm1), cm2);
    mx[2] = fmaxf(fmaxf(cm1, cm2), cm3);
    mx[3] = fmaxf(fmaxf(cm2, cm3), cr);
    #pragma unroll
    for (int j = 0; j < 4; ++j) {
        if (cen[j] == mx[j]) {
            float s = 1.0f / (1.0f + expf(-cen[j]));   // same expr as validated
            u32 pix = (u32)(y * W_ + x0 + j);
            u32 p = atomicAdd(&lcnt, 1u);
            if (p < BCAP)
                lc[p] = ((u64)__float_as_uint(s) << 32) | (u32)(~pix);
        }
    }
    __syncthreads();
    u32 c = lcnt; if (c > BCAP) c = BCAP;
    if (tid < c) segbuf[(size_t)gb * BCAP + tid] = lc[tid];
    if (tid == 0) segcnt[gb] = c;
}

// ---------------------------------------------------------------------------
// K2: exact per-row top-100 (lax.top_k semantics). Deterministic prefix-
// compaction of the row's 30 segments into LDS (no atomics, coalesced),
// then the validated two-round radix cut + rank-select.
// ---------------------------------------------------------------------------
__global__ __launch_bounds__(NTHR) void select_kernel(
    const u64* __restrict__ segbuf, const u32* __restrict__ segcnt,
    u32* __restrict__ tkKey, u32* __restrict__ tkIdx)
{
    const int row = blockIdx.x;
    const int tid = threadIdx.x;
    const int lane = tid & 63;

    __shared__ u64 cand[4096];      // 32 KB
    __shared__ u32 hist[4096];      // 16 KB
    __shared__ u64 cand2[2048];     // 16 KB
    __shared__ u32 cnts[BPR], pfx[BPR + 1];
    __shared__ u32 selb1, selG1, selb2;
    __shared__ u32 cnt2;

    if (tid == 0) cnt2 = 0;
    if (tid < BPR) cnts[tid] = segcnt[row * BPR + tid];
    #pragma unroll
    for (int j = 0; j < 4; ++j) hist[tid + j * NTHR] = 0;
    __syncthreads();                                            // B1
    if (tid == 0) {
        u32 a = 0;
        for (int s = 0; s < BPR; ++s) { pfx[s] = a; a += cnts[s]; }
        pfx[BPR] = a;
    }
    __syncthreads();                                            // B2
    u32 n = pfx[BPR]; if (n > 4096) n = 4096;

    // ---- deterministic compaction into LDS ----
    for (int i = tid; i < BPR * BCAP; i += NTHR) {
        int s = i >> 8, l = i & (BCAP - 1);
        if ((u32)l < cnts[s]) {
            u32 d = pfx[s] + l;
            if (d < 4096) cand[d] = segbuf[(size_t)(row * BPR + s) * BCAP + l];
        }
    }
    __syncthreads();                                            // B3

    // ---- round 1: histogram key[31:20] ----
    for (u32 i = tid; i < n; i += NTHR)
        atomicAdd(&hist[(u32)(cand[i] >> 52)], 1u);
    __syncthreads();                                            // B4
    if (tid < 64) {
        u32 v[4], t[4];
        #pragma unroll
        for (int k = 0; k < 4; ++k) {
            u32 s = 0; int b0 = (lane * 4 + k) * 16;
            #pragma unroll
            for (int qq = 0; qq < 16; ++qq) s += hist[b0 + qq];
            v[k] = s;
        }
        t[3] = v[3]; t[2] = v[2] + t[3]; t[1] = v[1] + t[2]; t[0] = v[0] + t[1];
        u32 lt = t[0], s = lt;
        #pragma unroll
        for (int d = 1; d < 64; d <<= 1) {
            u32 o = __shfl_down(s, d);
            if (lane + d < 64) s += o;
        }
        u32 SH = s - lt;
        u32 sfx[5] = {t[0] + SH, t[1] + SH, t[2] + SH, t[3] + SH, SH};
        #pragma unroll
        for (int k = 0; k < 4; ++k) {
            if (sfx[k] >= KTOP && sfx[k + 1] < KTOP) {
                u32 run = sfx[k + 1];
                int c = lane * 4 + k;
                for (int bin = c * 16 + 15; bin >= c * 16; --bin) {
                    u32 h = hist[bin];
                    if (run + h >= KTOP) { selb1 = (u32)bin; selG1 = run; break; }
                    run += h;
                }
            }
        }
    }
    __syncthreads();                                            // B5
    const u32 b1 = selb1, G1 = selG1;

    // ---- round 2: histogram key[19:8] within bin b1 ----
    #pragma unroll
    for (int j = 0; j < 4; ++j) hist[tid + j * NTHR] = 0;
    __syncthreads();                                            // B6
    for (u32 i = tid; i < n; i += NTHR) {
        u32 k = (u32)(cand[i] >> 32);
        if ((k >> 20) == b1) atomicAdd(&hist[(k >> 8) & 0xFFFu], 1u);
    }
    __syncthreads();                                            // B7
    {
        const u32 K2 = KTOP - G1;                 // >= 1
        if (tid < 64) {
            u32 v[4], t[4];
            #pragma unroll
            for (int k = 0; k < 4; ++k) {
                u32 s = 0; int b0 = (lane * 4 + k) * 16;
                #pragma unroll
                for (int qq = 0; qq < 16; ++qq) s += hist[b0 + qq];
                v[k] = s;
            }
            t[3] = v[3]; t[2] = v[2] + t[3]; t[1] = v[1] + t[2]; t[0] = v[0] + t[1];
            u32 lt = t[0], s = lt;
            #pragma unroll
            for (int d = 1; d < 64; d <<= 1) {
                u32 o = __shfl_down(s, d);
                if (lane + d < 64) s += o;
            }
            u32 SH = s - lt;
            u32 sfx[5] = {t[0] + SH, t[1] + SH, t[2] + SH, t[3] + SH, SH};
            #pragma unroll
            for (int k = 0; k < 4; ++k) {
                if (sfx[k] >= K2 && sfx[k + 1] < K2) {
                    u32 run = sfx[k + 1];
                    int c = lane * 4 + k;
                    for (int bin = c * 16 + 15; bin >= c * 16; --bin) {
                        u32 h = hist[bin];
                        if (run + h >= K2) { selb2 = (u32)bin; break; }
                        run += h;
                    }
                }
            }
        }
    }
    __syncthreads();                                            // B8
    const u32 cut24 = (b1 << 12) | selb2;

    // ---- compact qualifiers (key[31:8] >= cut24) ----
    for (u32 i = tid; i < n; i += NTHR) {
        u64 v = cand[i];
        if ((u32)(v >> 40) >= cut24) {
            u32 p = atomicAdd(&cnt2, 1u);     // ~120 ops total
            if (p < 2048) cand2[p] = v;
        }
    }
    __syncthreads();                                            // B9
    u32 q = cnt2; if (q > 2048) q = 2048;

    if (q <= NTHR) {
        // ---- rank-select, direct global write ----
        if (tid < (int)q) {
            u64 v = cand2[tid];
            u32 rank = 0;
            for (u32 i = 0; i < q; ++i) rank += (cand2[i] > v);
            if (rank < KTOP) {
                tkKey[row * KTOP + rank] = (u32)(v >> 32);
                tkIdx[row * KTOP + rank] = ~(u32)v;
            }
        }
    } else {
        // ---- fallback: bitonic sort (block-uniform branch) ----
        u32 npow = 128; while (npow < q) npow <<= 1;
        for (u32 i = q + tid; i < npow; i += NTHR) cand2[i] = 0ull;
        __syncthreads();
        for (u32 ks = 2; ks <= npow; ks <<= 1) {
            for (u32 j = ks >> 1; j > 0; j >>= 1) {
                for (u32 i = tid; i < npow; i += NTHR) {
                    u32 ix = i ^ j;
                    if (ix > i) {
                        u64 a = cand2[i], b = cand2[ix];
                        bool sw = ((i & ks) == 0) ? (a < b) : (a > b);
                        if (sw) { cand2[i] = b; cand2[ix] = a; }
                    }
                }
                __syncthreads();
            }
        }
        if (tid < KTOP) {
            u64 v = cand2[tid];
            tkKey[row * KTOP + tid] = (u32)(v >> 32);
            tkIdx[row * KTOP + tid] = ~(u32)v;
        }
    }
}

// ---------------------------------------------------------------------------
// Decode kernel (unchanged — validated absmax 0.0 incl. post-timing).
// ---------------------------------------------------------------------------
__global__ __launch_bounds__(320) void decode_kernel(
    const u32* __restrict__ tkKey, const u32* __restrict__ tkIdx,
    const float* __restrict__ wh,   const float* __restrict__ hps,
    const float* __restrict__ dimp, const float* __restrict__ rot,
    const float* __restrict__ prob, const float* __restrict__ reg,
    const float* __restrict__ hpo,  float* __restrict__ det)
{
    const int blk = blockIdx.x;
    const int b = blk / 9;
    const int j = blk - b * 9;
    const int tid = threadIdx.x;

    __shared__ u64 arr[300];
    __shared__ u64 selv[KTOP];
    __shared__ float hsv[KTOP], hxv[KTOP], hyv[KTOP];

    if (tid < 300) {
        int c = tid / 100, r = tid - c * 100;
        u32 key = tkKey[(b * 3 + c) * KTOP + r];
        arr[tid] = ((u64)key << 32) | (u32)(~(u32)tid);   // tid == c*K + r
    }
    __syncthreads();
    if (tid < 300) {
        u64 v = arr[tid];
        u32 rank = 0;
        for (int i = 0; i < 300; ++i) rank += (arr[i] > v);
        if (rank < KTOP) selv[rank] = v;
    }
    __syncthreads();

    float l = 0.f, t = 0.f, rr = 0.f, bb = 0.f, kxr = 0.f, kyr = 0.f;

    if (tid < KTOP) {
        int k = tid;
        u64 v = selv[k];
        u32 pos = ~(u32)v;
        if (pos > 299u) pos = 299u;
        u32 key = (u32)(v >> 32);
        int c = (int)pos / 100, r = (int)pos - c * 100;
        u32 sid = tkIdx[(b * 3 + c) * KTOP + r];
        if (sid > HW - 1) sid = HW - 1;
        float score = __uint_as_float(key);
        int yy = (int)sid / W_, xx = (int)sid - yy * W_;
        float xs0 = (float)xx, ys0 = (float)yy;
        float r0 = reg[((size_t)b * 2 + 0) * HW + sid];
        float r1 = reg[((size_t)b * 2 + 1) * HW + sid];
        float xsv = xs0 + r0, ysv = ys0 + r1;
        float w0 = wh[((size_t)b * 2 + 0) * HW + sid];
        float w1 = wh[((size_t)b * 2 + 1) * HW + sid];
        l  = xsv - w0 * 0.5f;
        t  = ysv - w1 * 0.5f;
        rr = xsv + w0 * 0.5f;
        bb = ysv + w1 * 0.5f;
        kxr = hps[((size_t)b * 18 + 2 * j)     * HW + sid] + xs0;
        kyr = hps[((size_t)b * 18 + 2 * j + 1) * HW + sid] + ys0;
        if (j == 0) {
            float* o = det + ((size_t)b * KTOP + k) * 45;
            o[0] = l * 4.0f; o[1] = t * 4.0f; o[2] = rr * 4.0f; o[3] = bb * 4.0f;
            o[4] = score;
            o[44] = (float)c;
        }
    } else if (tid < 200) {
        int r = tid - 100;
        int rw = 48 + b * 9 + j;
        u32 key = tkKey[rw * KTOP + r];
        u32 idx = tkIdx[rw * KTOP + r];
        if (idx > HW - 1) idx = HW - 1;
        float s = __uint_as_float(key);
        int yy = (int)idx / W_, xx = (int)idx - yy * W_;
        float hx = (float)xx + hpo[((size_t)b * 2 + 0) * HW + idx];
        float hy = (float)yy + hpo[((size_t)b * 2 + 1) * HW + idx];
        bool valid = s > 0.1f;
        hsv[r] = valid ? s : -1.0f;
        hxv[r] = valid ? hx : -10000.0f;
        hyv[r] = valid ? hy : -10000.0f;
    } else if (tid < 300 && j == 0) {
        int k = tid - 200;
        u64 v = selv[k];
        u32 pos = ~(u32)v;
        if (pos > 299u) pos = 299u;
        int c = (int)pos / 100, r = (int)pos - c * 100;
        u32 sid = tkIdx[(b * 3 + c) * KTOP + r];
        if (sid > HW - 1) sid = HW - 1;
        float* o = det + ((size_t)b * KTOP + k) * 45;
        #pragma unroll
        for (int qq = 0; qq < 3; ++qq)
            o[23 + qq] = dimp[((size_t)b * 3 + qq) * HW + sid];
        #pragma unroll
        for (int qq = 0; qq < 8; ++qq)
            o[35 + qq] = rot[((size_t)b * 8 + qq) * HW + sid];
        o[43] = prob[(size_t)b * HW + sid];
    }
    __syncthreads();

    if (tid < KTOP) {
        int k = tid;
        float best = INFINITY; int bi = 0;
        for (int m = 0; m < 100; ++m) {
            float dx = kxr - hxv[m];
            float dy = kyr - hyv[m];
            float d2 = __fadd_rn(__fmul_rn(dx, dx), __fmul_rn(dy, dy));
            float d = __fsqrt_rn(d2);
            if (d < best) { best = d; bi = m; }
        }
        float ss = hsv[bi], hx = hxv[bi], hy = hyv[bi];
        float th = __fmul_rn(fmaxf(__fsub_rn(bb, t), __fsub_rn(rr, l)), 0.3f);
        bool invalid = (hx < l) | (hx > rr) | (hy < t) | (hy > bb) |
                       (ss < 0.1f) | (best > th);
        float ox = invalid ? kxr : hx;
        float oy = invalid ? kyr : hy;
        float* o = det + ((size_t)b * KTOP + k) * 45;
        o[5 + 2 * j] = ox * 4.0f;
        o[6 + 2 * j] = oy * 4.0f;
        o[26 + j]    = ss;
    }
}

// ---------------------------------------------------------------------------
extern "C" void kernel_launch(void* const* d_in, const int* in_sizes, int n_in,
                              void* d_out, int out_size, void* d_ws, size_t ws_size,
                              hipStream_t stream) {
    const float* hm    = (const float*)d_in[0];
    const float* wh    = (const float*)d_in[1];
    const float* hps   = (const float*)d_in[2];
    const float* dimp  = (const float*)d_in[3];
    const float* rot   = (const float*)d_in[4];
    const float* prob  = (const float*)d_in[5];
    const float* reg   = (const float*)d_in[6];
    const float* hm_hp = (const float*)d_in[7];
    const float* hpo   = (const float*)d_in[8];
    float* det = (float*)d_out;

    u64* segbuf = (u64*)d_ws;                           // 5760*256 u64 = 11.8 MB
    u32* segcnt = (u32*)(segbuf + (size_t)NIMG * BPR * BCAP);  // 5760 u32
    u32* tkKey  = segcnt + NIMG * BPR;                  // 192*100 u32
    u32* tkIdx  = tkKey + NIMG * KTOP;                  // 192*100 u32

    nms_kernel<<<NIMG * BPR, 256, 0, stream>>>(hm, hm_hp, segbuf, segcnt);
    select_kernel<<<NIMG, NTHR, 0, stream>>>(segbuf, segcnt, tkKey, tkIdx);
    decode_kernel<<<B_ * 9, 320, 0, stream>>>(tkKey, tkIdx, wh, hps, dimp, rot,
                                              prob, reg, hpo, det);
}